// Round 2
// baseline (211.092 us; speedup 1.0000x reference)
//
#include <hip/hip_runtime.h>

#define SDIM 14
#define L_COORD 5.0f
#define L_NOOBJ 0.5f
#define BATCH 4096
#define CELLS (BATCH * SDIM * SDIM)   // 802816
#define BLOCK 128
#define NBLOCKS (CELLS / BLOCK)       // 6272
#define CELL_F 30
#define BLK_F (BLOCK * CELL_F)        // 3840 floats per tensor per block
#define BLK_F2 (BLK_F / 2)            // 1920 float2 per tensor per block

// LDS layout (floats). Box channels (0..9) of both tensors are transposed
// into compact per-cell rows; class channels (10..29) are consumed
// elementwise during staging: store (p-t) diffs, re-read per-cell in the
// SAME channel order as before -> bit-identical cls accumulation.
// Dcls stride 22 (not 20): breaks the 8-way bank conflict on per-cell reads
// (22t mod 32 has period 16 -> 4-way = 1.58x, vs stride 20's 8-way = 2.9x).
#define PBOX 0                        // [128][10]  box stride 10
#define TBOX (BLOCK * 10)             // [128][10]
#define DCLS (2 * BLOCK * 10)         // [128][22]  class-diff, stride 22
#define WSUM (DCLS + BLOCK * 22)      // [2]
#define LDS_FLOATS (WSUM + 2)         // 5378 floats = 21512 B -> 7 blocks/CU

__global__ __launch_bounds__(BLOCK, 4) void yolo_partial(
    const float* __restrict__ pred, const float* __restrict__ targ,
    float* __restrict__ partial) {
    __shared__ float lds[LDS_FLOATS];

    const int tid = threadIdx.x;
    const size_t base = (size_t)blockIdx.x * BLK_F;
    const float* P = pred + base;
    const float* T = targ + base;

    // ---- phase 1: fully coalesced loads (float2, never straddles a cell:
    //      element pair channels = (idx%15)*2 .. +1, both < 30) ----
    float2 p2[15], t2[15];
#pragma unroll
    for (int j = 0; j < 15; ++j) {
        const int idx = tid + j * BLOCK;          // 0..1919
        p2[j] = *reinterpret_cast<const float2*>(P + 2 * idx);
        t2[j] = *reinterpret_cast<const float2*>(T + 2 * idx);
    }

    // ---- phase 2: scatter box to LDS transpose; class -> diff store ----
#pragma unroll
    for (int j = 0; j < 15; ++j) {
        const int idx = tid + j * BLOCK;
        const int cell = idx / 15;
        const int c = (idx % 15) * 2;             // even channel 0..28
        if (c < 10) {
            *reinterpret_cast<float2*>(&lds[PBOX + cell * 10 + c]) = p2[j];
            *reinterpret_cast<float2*>(&lds[TBOX + cell * 10 + c]) = t2[j];
        } else {
            float2 d;
            d.x = p2[j].x - t2[j].x;
            d.y = p2[j].y - t2[j].y;
            *reinterpret_cast<float2*>(&lds[DCLS + cell * 22 + (c - 10)]) = d;
        }
    }
    __syncthreads();

    // ---- phase 3: per-cell compute from compact LDS ----
    float Pb[10], Tb[10];
#pragma unroll
    for (int j = 0; j < 5; ++j) {
        const float2 a = *reinterpret_cast<const float2*>(&lds[PBOX + tid * 10 + 2 * j]);
        const float2 b = *reinterpret_cast<const float2*>(&lds[TBOX + tid * 10 + 2 * j]);
        Pb[2 * j] = a.x; Pb[2 * j + 1] = a.y;
        Tb[2 * j] = b.x; Tb[2 * j + 1] = b.y;
    }

    // class loss: same channel order and expression shape as before
    float cls = 0.0f;
#pragma unroll
    for (int j = 0; j < 10; ++j) {
        const float2 d = *reinterpret_cast<const float2*>(&lds[DCLS + tid * 22 + 2 * j]);
        cls += d.x * d.x;
        cls += d.y * d.y;
    }

    // ---- branchless per-cell loss (identical arithmetic to prior round) ----
    const float d4 = Pb[4] - Tb[4];
    const float d9 = Pb[9] - Tb[9];
    const float noobj_l = L_NOOBJ * (d4 * d4 + d9 * d9);

    const float invS = 1.0f / (float)SDIM;
    const float t1x = Tb[0] * invS - Tb[2] * 0.5f;
    const float t1y = Tb[1] * invS - Tb[3] * 0.5f;
    const float t2x = Tb[0] * invS + Tb[2] * 0.5f;
    const float t2y = Tb[1] * invS + Tb[3] * 0.5f;
    const float area_t = (t2x - t1x) * (t2y - t1y);

    float iou0 = 0.0f, iou1 = 0.0f;
#pragma unroll
    for (int k = 0; k < 2; ++k) {
        const float bx = Pb[5 * k + 0], by = Pb[5 * k + 1];
        const float bw = Pb[5 * k + 2], bh = Pb[5 * k + 3];
        const float p1x = bx * invS - bw * 0.5f;
        const float p1y = by * invS - bh * 0.5f;
        const float p2x = bx * invS + bw * 0.5f;
        const float p2y = by * invS + bh * 0.5f;
        const float ltx = fmaxf(p1x, t1x), lty = fmaxf(p1y, t1y);
        const float rbx = fminf(p2x, t2x), rby = fminf(p2y, t2y);
        const float wx = fmaxf(rbx - ltx, 0.0f);
        const float wy = fmaxf(rby - lty, 0.0f);
        const float inter = wx * wy;
        const float area_p = (p2x - p1x) * (p2y - p1y);
        const float v = inter / (area_p + area_t - inter);
        if (k == 0) iou0 = v; else iou1 = v;
    }

    const bool pick1 = (iou0 <= iou1);
    const float iou_best = pick1 ? iou1 : iou0;
    const float psx = pick1 ? Pb[5] : Pb[0];
    const float psy = pick1 ? Pb[6] : Pb[1];
    const float psw = pick1 ? Pb[7] : Pb[2];
    const float psh = pick1 ? Pb[8] : Pb[3];
    const float psc = pick1 ? Pb[9] : Pb[4];
    const float tsx = pick1 ? Tb[5] : Tb[0];
    const float tsy = pick1 ? Tb[6] : Tb[1];
    const float tsw = pick1 ? Tb[7] : Tb[2];
    const float tsh = pick1 ? Tb[8] : Tb[3];

    const float dx = psx - tsx, dy = psy - tsy;
    const float dw = sqrtf(psw) - sqrtf(tsw);   // inputs in [0.01,1]: safe
    const float dh = sqrtf(psh) - sqrtf(tsh);
    const float reg = dx * dx + dy * dy + dw * dw + dh * dh;
    const float dconf = psc - iou_best;
    const float obj_l = cls + L_COORD * reg + dconf * dconf;

    float loss = (Tb[4] > 0.0f) ? obj_l : noobj_l;

    // ---- wave (64-lane) shuffle reduction ----
#pragma unroll
    for (int off = 32; off > 0; off >>= 1)
        loss += __shfl_down(loss, off, 64);

    const int lane = tid & 63;
    const int wave = tid >> 6;
    if (lane == 0) lds[WSUM + wave] = loss;
    __syncthreads();
    if (tid == 0)
        partial[blockIdx.x] = lds[WSUM + 0] + lds[WSUM + 1];
}

__global__ __launch_bounds__(256) void yolo_final(
    const float* __restrict__ partial, float* __restrict__ out) {
    float s = 0.0f;
    for (int i = threadIdx.x; i < NBLOCKS; i += 256) s += partial[i];
#pragma unroll
    for (int off = 32; off > 0; off >>= 1)
        s += __shfl_down(s, off, 64);
    __shared__ float wsum[256 / 64];
    const int lane = threadIdx.x & 63;
    const int wave = threadIdx.x >> 6;
    if (lane == 0) wsum[wave] = s;
    __syncthreads();
    if (threadIdx.x == 0)
        out[0] = (wsum[0] + wsum[1] + wsum[2] + wsum[3]) * (1.0f / (float)BATCH);
}

extern "C" void kernel_launch(void* const* d_in, const int* in_sizes, int n_in,
                              void* d_out, int out_size, void* d_ws, size_t ws_size,
                              hipStream_t stream) {
    const float* pred = (const float*)d_in[0];
    const float* targ = (const float*)d_in[1];
    float* out = (float*)d_out;
    float* partial = (float*)d_ws;   // NBLOCKS floats = 24.5 KB scratch

    yolo_partial<<<NBLOCKS, BLOCK, 0, stream>>>(pred, targ, partial);
    yolo_final<<<1, 256, 0, stream>>>(partial, out);
}